// Round 10
// baseline (234.766 us; speedup 1.0000x reference)
//
#include <hip/hip_runtime.h>
#include <climits>

#define N_ 16384
#define C_ 16
#define H_ 256
#define W_ 704
#define HW_ (H_*W_)
#define NC_ (N_*C_)
#define EPS_ 1e-3f
#define HDR_ 512

typedef unsigned long long ull;

// ---- workspace layout (float units) ----
// ints [2..5]: min_y, max_y, min_x, max_x
// [136..151] kA  [152..167] kC   [168..183] fcA [184..199] fcC
// [200..215] tA  [216..231] tC
// [264] cy [265] cx [266] inv_my [267] inv_mx
#define FLIN_  (HDR_ + 8*NC_)
#define VAL_   (HDR_ + 9*NC_)
#define KNNI_  (VAL_ + HW_*16)
#define PARTF_ (KNNI_ + 378256)
#define PS_    (PARTF_ + 16384)
#define GP_    (PS_ + 17408)
#define IMFT_  (GP_ + 640)

#define CAP_ 6144
#define PPB_ 32   // points per mega block

#define LOAD16(dst, src) { const float4* _s=(const float4*)(src); float4 _a=_s[0],_b=_s[1],_c=_s[2],_d=_s[3]; \
  dst[0]=_a.x;dst[1]=_a.y;dst[2]=_a.z;dst[3]=_a.w; dst[4]=_b.x;dst[5]=_b.y;dst[6]=_b.z;dst[7]=_b.w; \
  dst[8]=_c.x;dst[9]=_c.y;dst[10]=_c.z;dst[11]=_c.w; dst[12]=_d.x;dst[13]=_d.y;dst[14]=_d.z;dst[15]=_d.w; }

#define STORE16(dst, src) { float4* _d=(float4*)(dst); \
  _d[0]=make_float4(src[0],src[1],src[2],src[3]); _d[1]=make_float4(src[4],src[5],src[6],src[7]); \
  _d[2]=make_float4(src[8],src[9],src[10],src[11]); _d[3]=make_float4(src[12],src[13],src[14],src[15]); }

__global__ __launch_bounds__(256) void k_init(float* ws){
  if (blockIdx.x < 176){
    int4* c = (int4*)(ws + KNNI_);
    c[blockIdx.x*256 + threadIdx.x] = make_int4(0,0,0,0);
  } else if (threadIdx.x == 0){
    int* ih = (int*)ws;
    ih[2]=INT_MAX; ih[3]=INT_MIN; ih[4]=INT_MAX; ih[5]=INT_MIN;
  }
}

// blocks 0..63: pf/grid moments + cell counts + min/max
// blocks 64..767: val projection + imfT transpose (both coalesced)
__global__ __launch_bounds__(256) void k_statsprep(
    const float* __restrict__ pf, const float* __restrict__ imf,
    const int* __restrict__ grid,
    const float* __restrict__ Wval, const float* __restrict__ bval,
    float* __restrict__ ws)
{
  int t = threadIdx.x;
  if (blockIdx.x < 64){
    __shared__ float sP[4096];
    __shared__ double sDP[20];
    __shared__ int sh[16];
    int i = blockIdx.x*256 + t;
    { const float4* s4=(const float4*)(pf+i*16);
      float4* d4=(float4*)(sP+t*16);
      d4[0]=s4[0]; d4[1]=s4[1]; d4[2]=s4[2]; d4[3]=s4[3]; }
    int2 g = ((const int2*)grid)[i];
    int* counts = (int*)(ws + KNNI_);
    atomicAdd(&counts[g.x*W_ + g.y], 1);
    int mny=g.x,mxy=g.x,mnx=g.y,mxx=g.y;
#pragma unroll
    for (int o=32;o>0;o>>=1){
      mny=min(mny,__shfl_down(mny,o)); mxy=max(mxy,__shfl_down(mxy,o));
      mnx=min(mnx,__shfl_down(mnx,o)); mxx=max(mxx,__shfl_down(mxx,o));
    }
    int wv = t>>6;
    if ((t&63)==0){ sh[wv]=mny; sh[4+wv]=mxy; sh[8+wv]=mnx; sh[12+wv]=mxx; }
    double yy=(double)g.x, xx=(double)g.y;
    double m0=yy,m1=xx,m2=yy*yy,m3=xx*xx,m4=yy*xx;
#pragma unroll
    for (int o=32;o>0;o>>=1){
      m0+=__shfl_down(m0,o); m1+=__shfl_down(m1,o); m2+=__shfl_down(m2,o);
      m3+=__shfl_down(m3,o); m4+=__shfl_down(m4,o);
    }
    if ((t&63)==0){ sDP[wv*5]=m0; sDP[wv*5+1]=m1; sDP[wv*5+2]=m2; sDP[wv*5+3]=m3; sDP[wv*5+4]=m4; }
    __syncthreads();
    if (t==0){
      int* ih=(int*)ws;
      atomicMin(&ih[2],min(min(sh[0],sh[1]),min(sh[2],sh[3])));
      atomicMax(&ih[3],max(max(sh[4],sh[5]),max(sh[6],sh[7])));
      atomicMin(&ih[4],min(min(sh[8],sh[9]),min(sh[10],sh[11])));
      atomicMax(&ih[5],max(max(sh[12],sh[13]),max(sh[14],sh[15])));
      double* GP=(double*)(ws+GP_)+blockIdx.x*5;
#pragma unroll
      for (int k=0;k<5;++k) GP[k]=sDP[k]+sDP[5+k]+sDP[10+k]+sDP[15+k];
    }
    float* PS = ws + PS_ + blockIdx.x*272;
    int a=t&15, b2=t>>4;
    float acc=0.f;
    for (int i2=0;i2<256;++i2) acc += sP[i2*16+a]*sP[i2*16+b2];
    PS[16+t]=acc;
    if (t<16){
      float s=0.f;
      for (int i2=0;i2<256;++i2) s += sP[i2*16+t];
      PS[t]=s;
    }
  } else {
    __shared__ float sW[256], sb[16];
    sW[t]=Wval[t];
    if (t<16) sb[t]=bval[t];
    __syncthreads();
    int pix=(blockIdx.x-64)*256+t;
    float a[16];
#pragma unroll
    for (int ci=0;ci<16;++ci) a[ci]=imf[ci*HW_+pix];
    STORE16(ws+IMFT_+pix*16, a);
    float o[16];
#pragma unroll
    for (int c=0;c<16;++c) o[c]=sb[c];
#pragma unroll
    for (int ci=0;ci<16;++ci){ float v=a[ci];
#pragma unroll
      for (int c=0;c<16;++c) o[c]+=v*sW[ci*16+c];
    }
    STORE16(ws+VAL_+pix*16, o);
  }
}

__global__ __launch_bounds__(256) void k_scanA(float* ws){
  const int* counts = (const int*)(ws + KNNI_);
  int* bsum = (int*)(ws + KNNI_) + 180224 + 180240;
  int t = threadIdx.x;
  int v = counts[blockIdx.x*256 + t];
#pragma unroll
  for (int o=32;o>0;o>>=1) v += __shfl_down(v,o);
  __shared__ int w4[4];
  if ((t&63)==0) w4[t>>6] = v;
  __syncthreads();
  if (t==0) bsum[blockIdx.x] = w4[0]+w4[1]+w4[2]+w4[3];
}

// moment reduce + analytic BN coefs (k/fc/t) + center/scale + block-sum scan
__global__ __launch_bounds__(256) void k_scanB(
    const float* __restrict__ Wk, const float* __restrict__ bk,
    const float* __restrict__ gk, const float* __restrict__ betak,
    const float* __restrict__ Wfc, const float* __restrict__ bfc,
    const float* __restrict__ gfc, const float* __restrict__ betafc,
    const float* __restrict__ Wt, const float* __restrict__ bt,
    const float* __restrict__ gt, const float* __restrict__ betat,
    float* __restrict__ ws)
{
  __shared__ float sS[256], sSum[16];
  __shared__ float skA[16], skC[16];
  __shared__ double sG[5];
  __shared__ float sCtr[4];
  int t = threadIdx.x;
  const float* PS = ws + PS_;
  float acc=0.f, acc2=0.f;
  for (int b=0;b<64;++b){
    acc += PS[b*272 + t];
    if (t<16) acc2 += PS[b*272 + 256 + t];
  }
  if (t<16){ sSum[t]=acc; sS[240+t]=acc2; }
  else sS[t-16]=acc;
  if (t<5){
    const double* GP=(const double*)(ws+GP_);
    double s=0.0;
    for (int b=0;b<64;++b) s += GP[b*5+t];
    sG[t]=s;
  }
  __syncthreads();
  if (t==0){
    const int* ih=(const int*)ws;
    float cy=(float)(sG[0]/(double)N_), cx=(float)(sG[1]/(double)N_);
    float my=fmaxf((float)ih[3]-cy, cy-(float)ih[2]);
    float mx=fmaxf((float)ih[5]-cx, cx-(float)ih[4]);
    if (my==0.f) my=1.f;
    if (mx==0.f) mx=1.f;
    sCtr[0]=cy; sCtr[1]=cx; sCtr[2]=1.f/my; sCtr[3]=1.f/mx;
    ws[264]=cy; ws[265]=cx; ws[266]=sCtr[2]; ws[267]=sCtr[3];
  }
  __syncthreads();
  const float invN = 1.f/(float)N_;
  if (t<16){
    float wc[16];
#pragma unroll
    for (int j=0;j<16;++j) wc[j]=Wk[j*16+t];
    float dotS=0.f;
#pragma unroll
    for (int a2=0;a2<16;++a2) dotS+=sSum[a2]*wc[a2];
    float qd=0.f;
#pragma unroll
    for (int b2=0;b2<16;++b2){
      float inner=0.f;
#pragma unroll
      for (int a2=0;a2<16;++a2) inner+=wc[a2]*sS[b2*16+a2];
      qd+=wc[b2]*inner;
    }
    float bkc=bk[t];
    float mu = dotS*invN + bkc;
    float ex2 = qd*invN + 2.f*bkc*dotS*invN + bkc*bkc;
    float var = ex2 - mu*mu;
    float a = gk[t]/sqrtf(var+EPS_);
    skA[t]=a; skC[t]=betak[t]-mu*a;
    ws[136+t]=a; ws[152+t]=skC[t];
    float cy=sCtr[0], cx=sCtr[1], imy=sCtr[2], imx=sCtr[3];
    float Eyy=((float)(sG[2]/(double)N_) - cy*cy)*imy*imy;
    float Exx=((float)(sG[3]/(double)N_) - cx*cx)*imx*imx;
    float Eyx=((float)(sG[4]/(double)N_) - cy*cx)*imy*imx;
    float W0=Wfc[t], W1=Wfc[16+t];
    float varfc = Eyy*W0*W0 + 2.f*Eyx*W0*W1 + Exx*W1*W1;
    float afc = gfc[t]/sqrtf(varfc+EPS_);
    ws[168+t]=afc; ws[184+t]=betafc[t]-bfc[t]*afc;
  }
  __syncthreads();
  if (t<16){
    float Ac[16];
#pragma unroll
    for (int j=0;j<16;++j){
      float s=0.f;
#pragma unroll
      for (int m=0;m<16;++m) s += Wk[j*16+m]*skA[m]*Wt[m*16+t];
      Ac[j]=s;
    }
    float dc=bt[t];
#pragma unroll
    for (int m=0;m<16;++m) dc += (bk[m]*skA[m]+skC[m])*Wt[m*16+t];
    float dotS=0.f;
#pragma unroll
    for (int a2=0;a2<16;++a2) dotS+=sSum[a2]*Ac[a2];
    float qd=0.f;
#pragma unroll
    for (int b2=0;b2<16;++b2){
      float inner=0.f;
#pragma unroll
      for (int a2=0;a2<16;++a2) inner+=Ac[a2]*sS[b2*16+a2];
      qd+=Ac[b2]*inner;
    }
    float mu = dotS*invN + dc;
    float ex2 = qd*invN + 2.f*dc*dotS*invN + dc*dc;
    float var = ex2 - mu*mu;
    float a = gt[t]/sqrtf(var+EPS_);
    ws[200+t]=a; ws[216+t]=betat[t]-mu*a;
  }
  __syncthreads();
  int* bsum = (int*)(ws + KNNI_) + 180224 + 180240;
  int* boff = bsum + 704;
  __shared__ int sWsum[4];
  __shared__ int sCarry;
  int lane=t&63, wv=t>>6;
  if (t==0) sCarry=0;
  __syncthreads();
  for (int c=0;c<3;++c){
    int idx=c*256+t;
    int v0=(idx<704)?bsum[idx]:0;
    int v=v0;
#pragma unroll
    for (int o=1;o<64;o<<=1){ int xx=__shfl_up(v,o); if (lane>=o) v+=xx; }
    if (lane==63) sWsum[wv]=v;
    __syncthreads();
    int add=sCarry;
    for (int w2=0;w2<wv;++w2) add+=sWsum[w2];
    if (idx<704) boff[idx]=add+v-v0;
    __syncthreads();
    if (t==255) sCarry=add+v;
    __syncthreads();
  }
}

__global__ __launch_bounds__(256) void k_scanC(float* ws){
  int* counts = (int*)(ws + KNNI_);
  int* cellst = counts + 180224;
  const int* boff = counts + 180224 + 180240 + 704;
  __shared__ int sWsum[4];
  int t=threadIdx.x, lane=t&63, wv=t>>6;
  int i=blockIdx.x*256+t;
  int v0=counts[i], v=v0;
#pragma unroll
  for (int o=1;o<64;o<<=1){ int xx=__shfl_up(v,o); if (lane>=o) v+=xx; }
  if (lane==63) sWsum[wv]=v;
  __syncthreads();
  int add=boff[blockIdx.x];
  for (int w2=0;w2<wv;++w2) add+=sWsum[w2];
  int start=add+v-v0;
  cellst[i]=start;
  counts[i]=start;
  if (i==0) cellst[HW_]=N_;
}

__global__ __launch_bounds__(256) void k_scatter(const int* __restrict__ grid, float* __restrict__ ws){
  int i=blockIdx.x*256+threadIdx.x;
  int2 g=((const int2*)grid)[i];
  int* counts=(int*)(ws+KNNI_);
  unsigned* psort=(unsigned*)(counts+180224+180240+704+704);
  int pos=atomicAdd(&counts[g.x*W_+g.y],1);
  psort[pos]=((unsigned)g.x<<24)|((unsigned)g.y<<14)|(unsigned)i;
}

__device__ __forceinline__ void knn_insert(ull* arr, ull key){
  if (key < arr[8]){
    int q=8;
    while (q>0 && arr[q-1]>key){ arr[q]=arr[q-1]; --q; }
    arr[q]=key;
  }
}

__device__ __forceinline__ void scan_rows_global(const int* __restrict__ cellst,
                                                 const unsigned* __restrict__ psort,
                                                 int y, int x, int s,
                                                 int y0, int y1, int x0, int x1, ull* arr){
  for (int yy=y0+s; yy<=y1; yy+=4){
    int rowb=yy*W_;
    int st=cellst[rowb+x0];
    int e =cellst[rowb+x1+1];
    int dy=y-yy, dy2=dy*dy;
    for (int p=st;p<e;++p){
      unsigned u=psort[p];
      int px=(int)((u>>14)&1023);
      int dx=x-px;
      knn_insert(arr, ((ull)(unsigned)(dy2+dx*dx)<<14)|(ull)(u&16383u));
    }
  }
}

__device__ __forceinline__ void scan_rows_band(const unsigned* sBand, const int* sRowBase,
                                               int ya, int y, int x, int s,
                                               int y0, int y1, int x0, int x1, ull* arr){
  for (int yy=y0+s; yy<=y1; yy+=4){
    int j=yy-ya;
    int b=sRowBase[j], e=sRowBase[j+1];
    int lo=b, hi=e;
    while (lo<hi){ int mid=(lo+hi)>>1; int xm=(int)((sBand[mid]>>14)&1023); if (xm<x0) lo=mid+1; else hi=mid; }
    int dy=y-yy, dy2=dy*dy;
    for (int p=lo;p<e;++p){
      unsigned u=sBand[p];
      int px=(int)((u>>14)&1023);
      if (px>x1) break;
      int dx=x-px;
      knn_insert(arr, ((ull)(unsigned)(dy2+dx*dx)<<14)|(ull)(u&16383u));
    }
  }
}

// fused pipeline, 32 pts/block x 128 threads x 512 blocks (2+ blocks/CU co-resident)
__global__ __launch_bounds__(128) void k_mega(
    const float* __restrict__ pf, const int* __restrict__ grid,
    const float* __restrict__ Wk, const float* __restrict__ bk,
    const float* __restrict__ Wfc, const float* __restrict__ bfc,
    const float* __restrict__ Wt, const float* __restrict__ bt,
    const float* __restrict__ Woff, const float* __restrict__ boff,
    const float* __restrict__ Wattn, const float* __restrict__ battn,
    const float* __restrict__ Wout, const float* __restrict__ bout,
    const float* __restrict__ Wf, const float* __restrict__ bf,
    float* __restrict__ ws)
{
  __shared__ float sWk[256], sWt[256], sWattn[256], sWout[256];
  __shared__ float sWoff[512], sWf[512], sWfc[32];
  __shared__ float sbk[16], sbfc[16], sbt[16], sboff[32], sbattn[16], sbout[16], sbf[16];
  __shared__ float skA[16], skC[16], sfcA[16], sfcC[16], stA[16], stC[16];
  __shared__ float sCtr[4];
  __shared__ unsigned sMe[PPB_];
  __shared__ int sMn, sMx;
  __shared__ unsigned sBand[CAP_];
  __shared__ int sRowBase[80];
  __shared__ float sTl[512], sNei[512], sOf[1024], sAt[512], sSamp[512], sImg[512];
  __shared__ float sPart[64];

  const int* cellst = (const int*)(ws+KNNI_)+180224;
  const unsigned* psort = (const unsigned*)((const int*)(ws+KNNI_)+180224+180240+704+704);
  int tid=threadIdx.x, lane=tid&63;
  for (int j=tid;j<256;j+=128){ sWk[j]=Wk[j]; sWt[j]=Wt[j]; sWattn[j]=Wattn[j]; sWout[j]=Wout[j]; }
  for (int j=tid;j<512;j+=128){ sWoff[j]=Woff[j]; sWf[j]=Wf[j]; }
  if (tid<32){ sWfc[tid]=Wfc[tid]; sboff[tid]=boff[tid]; }
  if (tid<16){
    sbk[tid]=bk[tid]; sbfc[tid]=bfc[tid]; sbt[tid]=bt[tid]; sbattn[tid]=battn[tid];
    sbout[tid]=bout[tid]; sbf[tid]=bf[tid];
    skA[tid]=ws[136+tid]; skC[tid]=ws[152+tid];
    sfcA[tid]=ws[168+tid]; sfcC[tid]=ws[184+tid];
    stA[tid]=ws[200+tid]; stC[tid]=ws[216+tid];
  }
  if (tid<4) sCtr[tid]=ws[264+tid];
  if (tid==0){ sMn=INT_MAX; sMx=-1; }
  if (tid<PPB_) sMe[tid]=psort[blockIdx.x*PPB_+tid];
  __syncthreads();
  if (tid<PPB_){
    int yy=(int)(sMe[tid]>>24);
    atomicMin(&sMn,yy); atomicMax(&sMx,yy);
  }
  __syncthreads();
  int ya=max(sMn-16,0), yb=min(sMx+16,H_-1);
  int nr=yb-ya+1;
  int p0=cellst[ya*W_], p1=cellst[(yb+1)*W_];
  int count=p1-p0;
  bool fb=(count>CAP_)||(nr>78);
  // P1: threads 0..31 per-point compute; threads 32..127 load band
  if (tid<PPB_){
    unsigned me=sMe[tid];
    int i=(int)(me&16383u);
    float yf=(float)(me>>24), xf=(float)((me>>14)&1023u);
    float p[16]; LOAD16(p, pf+i*16);
    float ok[16];
#pragma unroll
    for (int c=0;c<16;++c) ok[c]=sbk[c];
#pragma unroll
    for (int j=0;j<16;++j){ float v=p[j];
#pragma unroll
      for (int c=0;c<16;++c) ok[c]+=v*sWk[j*16+c];
    }
    float ry=(yf-sCtr[0])*sCtr[2], rx=(xf-sCtr[1])*sCtr[3];
    float pts[16], q[16];
#pragma unroll
    for (int c=0;c<16;++c){
      pts[c]=ok[c]*skA[c]+skC[c];
      float pos=ry*sWfc[c]+rx*sWfc[16+c]+sbfc[c];
      q[c]=pts[c]+pos*sfcA[c]+sfcC[c];
    }
    float tv[16];
#pragma unroll
    for (int c=0;c<16;++c) tv[c]=sbt[c];
#pragma unroll
    for (int j=0;j<16;++j){ float v=pts[j];
#pragma unroll
      for (int c=0;c<16;++c) tv[c]+=v*sWt[j*16+c];
    }
#pragma unroll
    for (int c=0;c<16;++c) sTl[tid*16+c]=fmaxf(tv[c]*stA[c]+stC[c],0.f);
    float ov[32];
#pragma unroll
    for (int o=0;o<32;++o) ov[o]=sboff[o];
#pragma unroll
    for (int j=0;j<16;++j){ float v=q[j];
#pragma unroll
      for (int o=0;o<32;++o) ov[o]+=v*sWoff[j*32+o];
    }
#pragma unroll
    for (int o=0;o<32;++o) sOf[tid*32+o]=ov[o];
    float l[16];
#pragma unroll
    for (int c=0;c<16;++c) l[c]=sbattn[c];
#pragma unroll
    for (int j=0;j<16;++j){ float v=q[j];
#pragma unroll
      for (int c=0;c<16;++c) l[c]+=v*sWattn[j*16+c];
    }
#pragma unroll
    for (int h=0;h<4;++h){
      float m=fmaxf(fmaxf(l[h*4],l[h*4+1]),fmaxf(l[h*4+2],l[h*4+3]));
      float e0=expf(l[h*4]-m),e1=expf(l[h*4+1]-m),e2=expf(l[h*4+2]-m),e3=expf(l[h*4+3]-m);
      float inv=1.f/(e0+e1+e2+e3);
      sAt[tid*16+h*4]=e0*inv; sAt[tid*16+h*4+1]=e1*inv;
      sAt[tid*16+h*4+2]=e2*inv; sAt[tid*16+h*4+3]=e3*inv;
    }
  } else {
    int tt=tid-PPB_;
    if (!fb){
      for (int j=tt;j<count;j+=96) sBand[j]=psort[p0+j];
      for (int j=tt;j<=nr;j+=96) sRowBase[j]=cellst[(ya+j)*W_]-p0;
    }
  }
  __syncthreads();
  // P2: KNN, 4 scanner lanes per point
  int s=tid&3, pl=tid>>2;
  unsigned meK=sMe[pl];
  int y=(int)(meK>>24), x=(int)((meK>>14)&1023u);
  int r=8;
  { int y0=max(y-8,0),y1=min(y+8,H_-1),x0=max(x-8,0),x1=min(x+8,W_-1);
    if ((y1-y0+1)*(x1-x0+1)<224) r=16; }
  ull arr[9];
#pragma unroll
  for (int q2=0;q2<9;++q2) arr[q2]=~0ull;
  {
    int y0=max(y-r,0),y1=min(y+r,H_-1),x0=max(x-r,0),x1=min(x+r,W_-1);
    if (!fb) scan_rows_band(sBand,sRowBase,ya,y,x,s,y0,y1,x0,x1,arr);
    else     scan_rows_global(cellst,psort,y,x,s,y0,y1,x0,x1,arr);
  }
  ull m[9];
  bool done=false;
  {
    ull k[9];
#pragma unroll
    for (int q2=0;q2<9;++q2) m[q2]=~0ull;
    int base=lane&~3;
    for (int ss=0;ss<4;++ss){
#pragma unroll
      for (int q2=0;q2<9;++q2) k[q2]=__shfl(arr[q2],base+ss);
      for (int q3=0;q3<9;++q3){
        ull kk=k[q3];
        if (kk>=m[8]) break;
        int q=8; while (q>0&&m[q-1]>kk){ m[q]=m[q-1]; --q; } m[q]=kk;
      }
    }
    int y0=max(y-r,0),y1=min(y+r,H_-1),x0=max(x-r,0),x1=min(x+r,W_-1);
    bool covered=(y0==0)&&(y1==H_-1)&&(x0==0)&&(x1==W_-1);
    bool ok2=covered;
    if (!ok2 && m[8]!=~0ull){ int d9=(int)(m[8]>>14); ok2 = d9 < (r+1)*(r+1); }
    done=ok2;
  }
  while (__ballot(!done)){
    if (!done){
      r<<=1;
      int y0=max(y-r,0),y1=min(y+r,H_-1),x0=max(x-r,0),x1=min(x+r,W_-1);
#pragma unroll
      for (int q2=0;q2<9;++q2) arr[q2]=~0ull;
      if (!fb && r<=16) scan_rows_band(sBand,sRowBase,ya,y,x,s,y0,y1,x0,x1,arr);
      else              scan_rows_global(cellst,psort,y,x,s,y0,y1,x0,x1,arr);
    }
    ull k[9];
    bool doIns=!done;
    if (doIns){
#pragma unroll
      for (int q2=0;q2<9;++q2) m[q2]=~0ull;
    }
    int base=lane&~3;
    for (int ss=0;ss<4;++ss){
#pragma unroll
      for (int q2=0;q2<9;++q2) k[q2]=__shfl(arr[q2],base+ss);
      if (doIns){
        for (int q3=0;q3<9;++q3){
          ull kk=k[q3];
          if (kk>=m[8]) break;
          int q=8; while (q>0&&m[q-1]>kk){ m[q]=m[q-1]; --q; } m[q]=kk;
        }
      }
    }
    if (!done){
      int y0=max(y-r,0),y1=min(y+r,H_-1),x0=max(x-r,0),x1=min(x+r,W_-1);
      bool covered=(y0==0)&&(y1==H_-1)&&(x0==0)&&(x1==W_-1);
      bool ok2=covered;
      if (!ok2 && m[8]!=~0ull){ int d9=(int)(m[8]>>14); ok2 = d9 < (r+1)*(r+1); }
      if (ok2) done=true;
    }
  }
  // neighbor-feature mean from imfT: translate neighbor POINT index -> PIXEL via grid
  {
    const float* imfT = ws + IMFT_;
    int pixn[8];
#pragma unroll
    for (int nb=0;nb<8;++nb){
      int idx=(int)(m[nb+1]&16383ull);
      int2 g2=((const int2*)grid)[idx];
      pixn[nb]=g2.x*W_+g2.y;
    }
    float4 v[8];
#pragma unroll
    for (int nb=0;nb<8;++nb) v[nb]=*(const float4*)(imfT+pixn[nb]*16+s*4);
    float4 acc=make_float4(0.f,0.f,0.f,0.f);
#pragma unroll
    for (int nb=0;nb<8;++nb){
      acc.x+=v[nb].x; acc.y+=v[nb].y; acc.z+=v[nb].z; acc.w+=v[nb].w;
    }
    ((float4*)sNei)[tid]=make_float4(acc.x*0.125f,acc.y*0.125f,acc.z*0.125f,acc.w*0.125f);
  }
  __syncthreads();
  // P3: deformable attn (branchless batched gather) + Wout + fuse + f-partials
  {
    int p=tid>>2, h=tid&3;
    unsigned meA=sMe[p];
    float yf=(float)(meA>>24), xf=(float)((meA>>14)&1023u);
    const float4* val4=(const float4*)(ws+VAL_);
    int addr[16];
    float wgt[16];
#pragma unroll
    for (int pt=0;pt<4;++pt){
      float a=sAt[p*16+h*4+pt];
      float ly=yf+sOf[p*32+h*8+pt*2], lx=xf+sOf[p*32+h*8+pt*2+1];
      float fy=floorf(ly), fx=floorf(lx);
      float wy=ly-fy, wx=lx-fx;
      int y0=(int)fy, x0=(int)fx;
#pragma unroll
      for (int k2=0;k2<4;++k2){
        int yy=y0+(k2>>1), xx=x0+(k2&1);
        bool valid=((unsigned)yy<(unsigned)H_)&&((unsigned)xx<(unsigned)W_);
        int yc=min(max(yy,0),H_-1), xc=min(max(xx,0),W_-1);
        addr[pt*4+k2]=(yc*W_+xc)*4+h;
        float ww=((k2>>1)?wy:(1.f-wy))*((k2&1)?wx:(1.f-wx));
        wgt[pt*4+k2]=valid?a*ww:0.f;
      }
    }
    float4 acc=make_float4(0.f,0.f,0.f,0.f);
#pragma unroll
    for (int b2=0;b2<2;++b2){
      float4 vv[8];
#pragma unroll
      for (int k2=0;k2<8;++k2) vv[k2]=val4[addr[b2*8+k2]];
#pragma unroll
      for (int k2=0;k2<8;++k2){
        float w2=wgt[b2*8+k2];
        acc.x+=w2*vv[k2].x; acc.y+=w2*vv[k2].y; acc.z+=w2*vv[k2].z; acc.w+=w2*vv[k2].w;
      }
    }
    ((float4*)sSamp)[tid]=acc;
    __syncthreads();
    float img[4];
#pragma unroll
    for (int k2=0;k2<4;++k2){ int cc=h*4+k2; img[k2]=sbout[cc]+sNei[p*16+cc]; }
#pragma unroll
    for (int j=0;j<16;++j){
      float v=sSamp[p*16+j];
#pragma unroll
      for (int k2=0;k2<4;++k2) img[k2]+=v*sWout[j*16+h*4+k2];
    }
    ((float4*)sImg)[tid]=make_float4(img[0],img[1],img[2],img[3]);
    __syncthreads();
    float fl[4];
#pragma unroll
    for (int k2=0;k2<4;++k2) fl[k2]=sbf[h*4+k2];
#pragma unroll
    for (int j=0;j<16;++j){
      float v1=sTl[p*16+j];
      float v2=fmaxf(sImg[p*16+j],0.f);
#pragma unroll
      for (int k2=0;k2<4;++k2){
        fl[k2]+=v1*sWf[j*16+h*4+k2];
        fl[k2]+=v2*sWf[(16+j)*16+h*4+k2];
      }
    }
    int i3=(int)(meA&16383u);
    ((float4*)(ws+FLIN_+i3*16))[h]=make_float4(fl[0],fl[1],fl[2],fl[3]);
    float s0=fl[0],s1=fl[1],s2=fl[2],s3=fl[3];
    float q0=fl[0]*fl[0],q1=fl[1]*fl[1],q2=fl[2]*fl[2],q3=fl[3]*fl[3];
#pragma unroll
    for (int o=32;o>=4;o>>=1){
      s0+=__shfl_down(s0,o); s1+=__shfl_down(s1,o); s2+=__shfl_down(s2,o); s3+=__shfl_down(s3,o);
      q0+=__shfl_down(q0,o); q1+=__shfl_down(q1,o); q2+=__shfl_down(q2,o); q3+=__shfl_down(q3,o);
    }
    int wave=tid>>6, lane2=tid&63;
    if (lane2<4){
      sPart[wave*32+lane2*4+0]=s0; sPart[wave*32+lane2*4+1]=s1;
      sPart[wave*32+lane2*4+2]=s2; sPart[wave*32+lane2*4+3]=s3;
      sPart[wave*32+16+lane2*4+0]=q0; sPart[wave*32+16+lane2*4+1]=q1;
      sPart[wave*32+16+lane2*4+2]=q2; sPart[wave*32+16+lane2*4+3]=q3;
    }
    __syncthreads();
    if (tid<32){
      float v=sPart[tid]+sPart[32+tid];
      (ws+PARTF_)[blockIdx.x*32+tid]=v;
    }
  }
}

// per-block redundant f-reduce (512 partials) + final BN+relu output
__global__ __launch_bounds__(256) void k_outf(const float* __restrict__ gf,
                                              const float* __restrict__ betaf,
                                              const float* __restrict__ ws,
                                              float* __restrict__ out){
  __shared__ float red[256];
  __shared__ float sA[16], sC[16];
  int t=threadIdx.x, slot=t&31, chunk=t>>5;
  const float* part=ws+PARTF_;
  float acc=0.f;
  for (int bb=chunk*64; bb<chunk*64+64; ++bb) acc+=part[bb*32+slot];
  red[t]=acc;
  __syncthreads();
  if (chunk==0){
    float v=red[slot];
#pragma unroll
    for (int k2=1;k2<8;++k2) v+=red[k2*32+slot];
    red[slot]=v;
  }
  __syncthreads();
  if (t<16){
    float mu=red[t]*(1.f/N_);
    float var=red[16+t]*(1.f/N_)-mu*mu;
    float a=gf[t]/sqrtf(var+EPS_);
    sA[t]=a; sC[t]=betaf[t]-mu*a;
  }
  __syncthreads();
  int base=blockIdx.x*4096+t*16;
  float fl[16]; LOAD16(fl, ws+FLIN_+base);
  float o[16];
#pragma unroll
  for (int c=0;c<16;++c) o[c]=fmaxf(fl[c]*sA[c]+sC[c],0.f);
  STORE16(out+base, o);
}

extern "C" void kernel_launch(void* const* d_in, const int* in_sizes, int n_in,
                              void* d_out, int out_size, void* d_ws, size_t ws_size,
                              hipStream_t stream)
{
  const float* pf    = (const float*)d_in[0];
  const float* imf   = (const float*)d_in[1];
  const int*   gridp = (const int*)d_in[2];
  const float* Wk   =(const float*)d_in[3],  *bk   =(const float*)d_in[4];
  const float* gk   =(const float*)d_in[5],  *betak=(const float*)d_in[6];
  const float* Wfc  =(const float*)d_in[7],  *bfc  =(const float*)d_in[8];
  const float* gfc  =(const float*)d_in[9],  *betafc=(const float*)d_in[10];
  const float* Wt   =(const float*)d_in[11], *bt   =(const float*)d_in[12];
  const float* gt   =(const float*)d_in[13], *betat=(const float*)d_in[14];
  const float* Woff =(const float*)d_in[15], *boff =(const float*)d_in[16];
  const float* Wattn=(const float*)d_in[17], *battn=(const float*)d_in[18];
  const float* Wval =(const float*)d_in[19], *bval =(const float*)d_in[20];
  const float* Wout =(const float*)d_in[21], *bout =(const float*)d_in[22];
  const float* Wf   =(const float*)d_in[23], *bf   =(const float*)d_in[24];
  const float* gf   =(const float*)d_in[25], *betaf=(const float*)d_in[26];
  float* ws  = (float*)d_ws;
  float* out = (float*)d_out;

  hipLaunchKernelGGL(k_init,      dim3(177),     dim3(256), 0, stream, ws);
  hipLaunchKernelGGL(k_statsprep, dim3(768),     dim3(256), 0, stream, pf, imf, gridp, Wval, bval, ws);
  hipLaunchKernelGGL(k_scanA,     dim3(704),     dim3(256), 0, stream, ws);
  hipLaunchKernelGGL(k_scanB,     dim3(1),       dim3(256), 0, stream,
                     Wk, bk, gk, betak, Wfc, bfc, gfc, betafc, Wt, bt, gt, betat, ws);
  hipLaunchKernelGGL(k_scanC,     dim3(704),     dim3(256), 0, stream, ws);
  hipLaunchKernelGGL(k_scatter,   dim3(N_/256),  dim3(256), 0, stream, gridp, ws);
  hipLaunchKernelGGL(k_mega,      dim3(N_/PPB_), dim3(128), 0, stream,
                     pf, gridp, Wk, bk, Wfc, bfc, Wt, bt, Woff, boff, Wattn, battn,
                     Wout, bout, Wf, bf, ws);
  hipLaunchKernelGGL(k_outf,      dim3(64),      dim3(256), 0, stream, gf, betaf, ws, out);
}